// Round 1
// baseline (1043.026 us; speedup 1.0000x reference)
//
#include <hip/hip_runtime.h>

// PairwiseGeometricBilinear: 3x equi_linear + sparse GP/JOIN bilinear on Cl(3,0,1), 16 blades.
// B*S = 16384 positions, C = 64 channels, f32 throughout.

#define N_POS   16384
#define TILE    4
#define NTILES  (N_POS / TILE)      // 4096
#define NBLK    256
#define SLICE   4096                // one 64x64 weight slice in LDS (words)
#define SX_STRIDE 68                // padded row stride for x tile (words)
#define SMEM_WORDS (8 * SLICE + 64 * SX_STRIDE)   // 32768 + 4352 = 37120 -> 148480 B

// ---------------- compile-time GA tables ----------------
namespace ga {
constexpr int MASKS[16] = {0,1,2,4,8,3,5,9,6,10,12,7,11,13,14,15};
constexpr int m2i(int m) { int r = 0; for (int i = 0; i < 16; ++i) if (MASKS[i] == m) r = i; return r; }
constexpr int popc4(int x) { return ((x>>0)&1) + ((x>>1)&1) + ((x>>2)&1) + ((x>>3)&1); }
constexpr int rsign(int a, int b) {            // reorder sign, e1..e3 square to +1
  int s = 0; a >>= 1;
  while (a) { s += popc4(a & b); a >>= 1; }
  return (s & 1) ? -1 : 1;
}
struct Tab {
  int kg[256]; int sg[256];   // geometric product: k-index and sign per (i,j)
  int kj[256]; int sj[256];   // join (regressive) product
  int gr[16];  int src[16];  int e0w[16]; int he0[16];
};
constexpr Tab make() {
  Tab t{};
  for (int i = 0; i < 16; ++i) {
    int m = MASKS[i];
    t.gr[i]  = popc4(m);
    t.he0[i] = m & 1;
    t.src[i] = m2i(m & ~1);
    t.e0w[i] = (m & 1) ? (4 + popc4(m)) : 0;   // 5 + (grade-1)
  }
  for (int i = 0; i < 16; ++i) for (int j = 0; j < 16; ++j) {
    int a = MASKS[i], bm = MASKS[j], idx = i*16 + j;
    t.kg[idx] = m2i(a ^ bm);
    t.sg[idx] = ((a & bm & 1) == 0) ? rsign(a, bm) : 0;
    if ((a | bm) == 15) {   // duals disjoint <=> union is pseudoscalar
      int mp = a ^ bm;      // mask of dual-wedge result
      t.kj[idx] = m2i(15 ^ mp);
      t.sj[idx] = rsign(a, 15 ^ a) * rsign(bm, 15 ^ bm) *
                  rsign(15 ^ a, 15 ^ bm) * rsign(mp, 15 ^ mp);
    } else { t.kj[idx] = 0; t.sj[idx] = 0; }
  }
  return t;
}
constexpr Tab T = make();
}

// wave k-grouping: waves get e0-uniform blade sets -> no e0-branch divergence
constexpr int KMAP[16] = {0,2,3,4, 1,5,6,7, 8,9,10,14, 11,12,13,15};

// ---------------- shared equi_linear tile compute ----------------
// sW: 8 slices [g-1][i][o] (grades 1..4 at 0..3, e0 slices 5..8 at 4..7); grade-0 slice read from global W.
// sx: [i_channel][n*16 + k_blade], stride SX_STRIDE.
__device__ __forceinline__ void eqlin_compute(
    const float* sW, const float* sx,
    const float* __restrict__ Wg, const float* __restrict__ bias,
    float* y, int p0)
{
  const int tid = threadIdx.x;
  const int kk  = KMAP[tid >> 4];
  const int og  = tid & 15;
  const int o0  = og * 4;
  const int g   = ga::T.gr[kk];
  const int sk  = ga::T.src[kk];
  const int ew  = ga::T.e0w[kk];
  const bool he = ga::T.he0[kk] != 0;

  float acc[TILE][4];
  #pragma unroll
  for (int n = 0; n < TILE; ++n)
    acc[n][0] = acc[n][1] = acc[n][2] = acc[n][3] = 0.f;

  const float* wmp = sW + (g > 0 ? (g - 1) : 0) * SLICE + o0;
  const float* wep = sW + (he ? (ew - 1) : 0) * SLICE + o0;
  const float* sxm = sx + kk;
  const float* sxs = sx + sk;

  #pragma unroll 4
  for (int i = 0; i < 64; ++i) {
    float4 wm;
    if (g > 0) {
      wm = *reinterpret_cast<const float4*>(wmp + i * 64);
    } else {   // only blade k==0 lanes: grade-0 slice from global (L1-resident)
      wm.x = Wg[((o0 + 0) * 64 + i) * 9];
      wm.y = Wg[((o0 + 1) * 64 + i) * 9];
      wm.z = Wg[((o0 + 2) * 64 + i) * 9];
      wm.w = Wg[((o0 + 3) * 64 + i) * 9];
    }
    float xm[TILE];
    #pragma unroll
    for (int n = 0; n < TILE; ++n) xm[n] = sxm[i * SX_STRIDE + n * 16];
    #pragma unroll
    for (int n = 0; n < TILE; ++n) {
      acc[n][0] = fmaf(wm.x, xm[n], acc[n][0]);
      acc[n][1] = fmaf(wm.y, xm[n], acc[n][1]);
      acc[n][2] = fmaf(wm.z, xm[n], acc[n][2]);
      acc[n][3] = fmaf(wm.w, xm[n], acc[n][3]);
    }
    if (he) {
      float4 we = *reinterpret_cast<const float4*>(wep + i * 64);
      #pragma unroll
      for (int n = 0; n < TILE; ++n) {
        float xs = sxs[i * SX_STRIDE + n * 16];
        acc[n][0] = fmaf(we.x, xs, acc[n][0]);
        acc[n][1] = fmaf(we.y, xs, acc[n][1]);
        acc[n][2] = fmaf(we.z, xs, acc[n][2]);
        acc[n][3] = fmaf(we.w, xs, acc[n][3]);
      }
    }
  }

  if (kk == 0) {   // bias on the scalar blade only
    float4 bb = *reinterpret_cast<const float4*>(bias + o0);
    #pragma unroll
    for (int n = 0; n < TILE; ++n) {
      acc[n][0] += bb.x; acc[n][1] += bb.y; acc[n][2] += bb.z; acc[n][3] += bb.w;
    }
  }

  #pragma unroll
  for (int n = 0; n < TILE; ++n)
    #pragma unroll
    for (int oo = 0; oo < 4; ++oo)
      y[((p0 + n) * 64 + o0 + oo) * 16 + kk] = acc[n][oo];
}

// stage W (64,64,9) -> LDS transposed slices [g-1][i][o] for g = 1..8
__device__ __forceinline__ void stage_W(float* sW, const float* __restrict__ W) {
  for (int idx = threadIdx.x; idx < 64 * 64 * 9; idx += 256) {
    float v = W[idx];
    int g = idx % 9;
    int rest = idx / 9;           // o*64 + i
    int i = rest & 63, o = rest >> 6;
    if (g >= 1) sW[(g - 1) * SLICE + i * 64 + o] = v;
  }
}

// ---------------- kernel 1/2: y = equi_linear(x, W, b) ----------------
__global__ __launch_bounds__(256) void eqlin_kernel(
    const float* __restrict__ x, const float* __restrict__ W,
    const float* __restrict__ b, float* __restrict__ y)
{
  extern __shared__ float smem[];
  float* sW = smem;
  float* sx = smem + 8 * SLICE;
  stage_W(sW, W);

  for (int t = blockIdx.x; t < NTILES; t += gridDim.x) {
    const int p0 = t * TILE;
    __syncthreads();   // previous tile's sx readers done
    for (int idx4 = threadIdx.x; idx4 < TILE * 256; idx4 += 256) {
      float4 v = *reinterpret_cast<const float4*>(x + (size_t)p0 * 1024 + idx4 * 4);
      int n = idx4 >> 8;
      int r = (idx4 * 4) & 1023;      // i*16 + k
      int i = r >> 4, k = r & 15;     // k % 4 == 0
      *reinterpret_cast<float4*>(&sx[i * SX_STRIDE + n * 16 + k]) = v;
    }
    __syncthreads();
    eqlin_compute(sW, sx, W, b, y, p0);
  }
}

// ---------------- kernel 3: bilinear(l, r) -> equi_linear(Wout) (in-place on l) ----------------
__global__ __launch_bounds__(256) void bilin_out_kernel(
    const float* l, const float* __restrict__ r,
    const float* __restrict__ W, const float* __restrict__ b, float* y)
{
  extern __shared__ float smem[];
  float* sW = smem;
  float* sx = smem + 8 * SLICE;
  stage_W(sW, W);

  const int n = threadIdx.x >> 6;   // position within tile
  const int c = threadIdx.x & 63;   // channel

  for (int t = blockIdx.x; t < NTILES; t += gridDim.x) {
    const int p0 = t * TILE;
    const size_t base = (size_t)((p0 + n) * 64 + c) * 16;
    float lv[16], rv[16];
    #pragma unroll
    for (int q = 0; q < 4; ++q) {
      *reinterpret_cast<float4*>(&lv[q * 4]) = *reinterpret_cast<const float4*>(l + base + q * 4);
      *reinterpret_cast<float4*>(&rv[q * 4]) = *reinterpret_cast<const float4*>(r + base + q * 4);
    }
    float mv[16];
    #pragma unroll
    for (int q = 0; q < 16; ++q) mv[q] = 0.f;

    if (c < 32) {   // geometric product channels
      #pragma unroll
      for (int i = 0; i < 16; ++i)
        #pragma unroll
        for (int j = 0; j < 16; ++j) {
          if (ga::T.sg[i * 16 + j] > 0)      mv[ga::T.kg[i * 16 + j]] += lv[i] * rv[j];
          else if (ga::T.sg[i * 16 + j] < 0) mv[ga::T.kg[i * 16 + j]] -= lv[i] * rv[j];
        }
    } else {        // join channels
      #pragma unroll
      for (int i = 0; i < 16; ++i)
        #pragma unroll
        for (int j = 0; j < 16; ++j) {
          if (ga::T.sj[i * 16 + j] > 0)      mv[ga::T.kj[i * 16 + j]] += lv[i] * rv[j];
          else if (ga::T.sj[i * 16 + j] < 0) mv[ga::T.kj[i * 16 + j]] -= lv[i] * rv[j];
        }
    }

    __syncthreads();   // previous tile's eqlin_compute done reading sx
    #pragma unroll
    for (int q = 0; q < 16; ++q) sx[c * SX_STRIDE + n * 16 + q] = mv[q];
    __syncthreads();
    eqlin_compute(sW, sx, W, b, y, p0);   // reads mid from sx, writes y tile (l already consumed)
  }
}

// ---------------- launch ----------------
extern "C" void kernel_launch(void* const* d_in, const int* in_sizes, int n_in,
                              void* d_out, int out_size, void* d_ws, size_t ws_size,
                              hipStream_t stream) {
  (void)in_sizes; (void)n_in; (void)out_size; (void)ws_size;
  const float* mv1 = (const float*)d_in[0];
  const float* mv2 = (const float*)d_in[1];
  const float* Wl  = (const float*)d_in[2];
  const float* bl  = (const float*)d_in[3];
  const float* Wr  = (const float*)d_in[4];
  const float* br  = (const float*)d_in[5];
  const float* Wo  = (const float*)d_in[6];
  const float* bo  = (const float*)d_in[7];
  float* out  = (float*)d_out;
  float* rbuf = (float*)d_ws;     // 67.1 MB for r

  const size_t smem = SMEM_WORDS * sizeof(float);
  eqlin_kernel<<<NBLK, 256, smem, stream>>>(mv1, Wl, bl, out);    // l -> d_out
  eqlin_kernel<<<NBLK, 256, smem, stream>>>(mv2, Wr, br, rbuf);   // r -> ws
  bilin_out_kernel<<<NBLK, 256, smem, stream>>>(out, rbuf, Wo, bo, out);
}

// Round 2
// 299.158 us; speedup vs baseline: 3.4865x; 3.4865x over previous
//
#include <hip/hip_runtime.h>

// PairwiseGeometricBilinear via bf16 MFMA: 3x equi_linear as per-blade GEMMs
// (M=64 out-ch, K=64/128 in-ch, N=positions) + sparse GP/JOIN bilinear.
// B*S = 16384 positions, C = 64 channels. l/r intermediates bf16 in d_ws.

#define NPOS   16384
#define TILE_P 16
#define NTILES (NPOS / TILE_P)   // 1024
#define NBLK   256
#define ITERS  (NTILES / NBLK)   // 4

typedef __attribute__((ext_vector_type(8))) short bf16x8;
typedef __attribute__((ext_vector_type(4))) float f32x4;

// ---------------- compile-time GA tables (verified in round 1) ----------------
namespace ga {
constexpr int MASKS[16] = {0,1,2,4,8,3,5,9,6,10,12,7,11,13,14,15};
constexpr int m2i(int m) { int r = 0; for (int i = 0; i < 16; ++i) if (MASKS[i] == m) r = i; return r; }
constexpr int popc4(int x) { return ((x>>0)&1) + ((x>>1)&1) + ((x>>2)&1) + ((x>>3)&1); }
constexpr int rsign(int a, int b) {
  int s = 0; a >>= 1;
  while (a) { s += popc4(a & b); a >>= 1; }
  return (s & 1) ? -1 : 1;
}
struct Tab {
  int kg[256]; int sg[256];
  int kj[256]; int sj[256];
  int gr[16];  int src[16];  int e0w[16]; int he0[16];
};
constexpr Tab make() {
  Tab t{};
  for (int i = 0; i < 16; ++i) {
    int m = MASKS[i];
    t.gr[i]  = popc4(m);
    t.he0[i] = m & 1;
    t.src[i] = m2i(m & ~1);
    t.e0w[i] = (m & 1) ? (4 + popc4(m)) : 0;
  }
  for (int i = 0; i < 16; ++i) for (int j = 0; j < 16; ++j) {
    int a = MASKS[i], bm = MASKS[j], idx = i*16 + j;
    t.kg[idx] = m2i(a ^ bm);
    t.sg[idx] = ((a & bm & 1) == 0) ? rsign(a, bm) : 0;
    if ((a | bm) == 15) {
      int mp = a ^ bm;
      t.kj[idx] = m2i(15 ^ mp);
      t.sj[idx] = rsign(a, 15 ^ a) * rsign(bm, 15 ^ bm) *
                  rsign(15 ^ a, 15 ^ bm) * rsign(mp, 15 ^ mp);
    } else { t.kj[idx] = 0; t.sj[idx] = 0; }
  }
  return t;
}
constexpr Tab T = make();
}

// ---------------- LDS word-offset maps ----------------
// kernel1/2: wA (9 slices, frag-linear bf16) | raw x f32 (padded rows) | lout (bf16 half)
#define WA_WORDS   18432                    // 9*4*2*64*4 words = 72 KB
#define RAW_OFF    18432
#define RAW_STRIDE 1033                     // 1024 + 9 pad words (odd*? -> 9p bank spread)
#define RAW_WORDS  (16 * RAW_STRIDE)        // 16528
#define LOUT_OFF   (RAW_OFF + RAW_WORDS)    // 34960
#define K1_WORDS   (LOUT_OFF + 4096)        // 39056 words = 156224 B
// kernel3: wA | mfrag (bf16 frag-linear) | lout f32 half (padded rows)
#define MF_OFF     18432
#define MF_WORDS   8192                     // 16*2*64*4
#define LF_OFF     (MF_OFF + MF_WORDS)      // 26624
#define K3_WORDS   (LF_OFF + 8 * 1025)      // 34824 words = 139296 B

__device__ __forceinline__ unsigned cvt_pk_bf16(float lo, float hi) {
  unsigned r;
  asm("v_cvt_pk_bf16_f32 %0, %1, %2" : "=v"(r) : "v"(lo), "v"(hi));
  return r;
}
__device__ __forceinline__ float bf2f(unsigned short us) {
  return __builtin_bit_cast(float, ((unsigned)us) << 16);
}

// stage W (64,64,9) f32 -> LDS bf16 A-fragments, frag-linear:
// word(s,mt,ks,l)*4 holds 8 bf16 = W[o = mt*16 + (l&15)][i = ks*32 + (l>>4)*8 + j][s]
__device__ __forceinline__ void stage_wA(unsigned* lds, const float* __restrict__ W) {
  for (int c = threadIdx.x; c < 4608; c += 1024) {
    int l  = c & 63;
    int ks = (c >> 6) & 1;
    int mt = (c >> 7) & 3;
    int s  = c >> 9;
    int o  = mt * 16 + (l & 15);
    int i0 = ks * 32 + ((l >> 4) << 3);
    const float* wp = W + (o * 64 + i0) * 9 + s;
    float f0 = wp[0],  f1 = wp[9],  f2 = wp[18], f3 = wp[27];
    float f4 = wp[36], f5 = wp[45], f6 = wp[54], f7 = wp[63];
    uint4 u;
    u.x = cvt_pk_bf16(f0, f1); u.y = cvt_pk_bf16(f2, f3);
    u.z = cvt_pk_bf16(f4, f5); u.w = cvt_pk_bf16(f6, f7);
    *reinterpret_cast<uint4*>(&lds[c * 4]) = u;
  }
}

// build MFMA B-frag for (blade, ks) from raw LDS x tile: lane l -> x[p=l&15][i=ks*32+(l>>4)*8+j][blade]
__device__ __forceinline__ bf16x8 build_frag(const float* ldsf, int p, int rg, int ks, int blade) {
  const float* base = ldsf + RAW_OFF + p * RAW_STRIDE + (ks * 32 + rg * 8) * 16 + blade;
  float f[8];
  #pragma unroll
  for (int j = 0; j < 8; ++j) f[j] = base[j * 16];
  union { bf16x8 v; unsigned u[4]; } r;
  #pragma unroll
  for (int j = 0; j < 4; ++j) r.u[j] = cvt_pk_bf16(f[2*j], f[2*j+1]);
  return r.v;
}

// ---------------- kernel 1/2: y(bf16 [p][k][c]) = equi_linear(x f32 [p][i][k]) ----------------
__global__ __launch_bounds__(1024) void eqlin_mfma(
    const float* __restrict__ x, const float* __restrict__ W,
    const float* __restrict__ bias, unsigned short* __restrict__ y)
{
  extern __shared__ unsigned lds[];
  stage_wA(lds, W);
  __syncthreads();

  const int tid  = threadIdx.x;
  const int wid  = tid >> 6;       // wave = blade
  const int lane = tid & 63;
  const int p    = lane & 15;
  const int rg   = lane >> 4;
  const int b    = wid;
  const int g    = ga::T.gr[b];
  const bool he  = ga::T.he0[b] != 0;
  const int ew   = he ? ga::T.e0w[b] : 0;
  const int sb   = ga::T.src[b];
  const float* ldsf = (const float*)lds;

  // hoist A-fragments into registers (reused across all tiles)
  bf16x8 amain[4][2], ae0[4][2];
  #pragma unroll
  for (int mt = 0; mt < 4; ++mt)
    #pragma unroll
    for (int ks = 0; ks < 2; ++ks) {
      amain[mt][ks] = *reinterpret_cast<const bf16x8*>(&lds[(((g*4 + mt)*2 + ks)*64 + lane)*4]);
      if (he)
        ae0[mt][ks] = *reinterpret_cast<const bf16x8*>(&lds[(((ew*4 + mt)*2 + ks)*64 + lane)*4]);
    }
  f32x4 bias4[4];
  if (b == 0) {
    #pragma unroll
    for (int mt = 0; mt < 4; ++mt)
      bias4[mt] = *reinterpret_cast<const f32x4*>(&bias[mt*16 + rg*4]);
  }

  unsigned* yw = (unsigned*)y;   // global word = 2 bf16 (k,c layout: word idx = pos*512 + k*32 + cp)

  for (int it = 0; it < ITERS; ++it) {
    const int tile = it * NBLK + blockIdx.x;
    const long tb  = (long)tile * TILE_P * 1024;

    // ---- stage raw x tile: wave wid stages its own p-row (16 x 256B chunks) ----
    #pragma unroll
    for (int seg = 0; seg < 16; ++seg) {
      const float* src = x + tb + wid * 1024 + seg * 64 + lane;
      unsigned* dst = &lds[RAW_OFF + wid * RAW_STRIDE + seg * 64];
      __builtin_amdgcn_global_load_lds((const __attribute__((address_space(1))) unsigned*)src,
                                       (__attribute__((address_space(3))) unsigned*)dst, 4, 0, 0);
    }
    asm volatile("s_waitcnt vmcnt(0)" ::: "memory");
    __syncthreads();

    // ---- B-frag build + MFMA ----
    f32x4 acc[4];
    #pragma unroll
    for (int mt = 0; mt < 4; ++mt) acc[mt] = (f32x4){0.f, 0.f, 0.f, 0.f};
    #pragma unroll
    for (int ks = 0; ks < 2; ++ks) {
      bf16x8 bb = build_frag(ldsf, p, rg, ks, b);
      #pragma unroll
      for (int mt = 0; mt < 4; ++mt)
        acc[mt] = __builtin_amdgcn_mfma_f32_16x16x32_bf16(amain[mt][ks], bb, acc[mt], 0, 0, 0);
    }
    if (he) {
      #pragma unroll
      for (int ks = 0; ks < 2; ++ks) {
        bf16x8 bs = build_frag(ldsf, p, rg, ks, sb);
        #pragma unroll
        for (int mt = 0; mt < 4; ++mt)
          acc[mt] = __builtin_amdgcn_mfma_f32_16x16x32_bf16(ae0[mt][ks], bs, acc[mt], 0, 0, 0);
      }
    }
    if (b == 0) {
      #pragma unroll
      for (int mt = 0; mt < 4; ++mt) acc[mt] += bias4[mt];
    }

    // ---- C-write (bf16, swizzled LDS) + coalesced flush, in p-halves ----
    #pragma unroll
    for (int h = 0; h < 2; ++h) {
      __syncthreads();
      if ((p >> 3) == h) {
        int pl = p & 7;
        #pragma unroll
        for (int mt = 0; mt < 4; ++mt) {
          unsigned u0 = cvt_pk_bf16(acc[mt].x, acc[mt].y);
          unsigned u1 = cvt_pk_bf16(acc[mt].z, acc[mt].w);
          int cp0 = mt*8 + rg*2;
          int w = LOUT_OFF + pl*512 + b*32 + (cp0 ^ (pl*2));
          uint2 v; v.x = u0; v.y = u1;
          *reinterpret_cast<uint2*>(&lds[w]) = v;
        }
      }
      __syncthreads();
      #pragma unroll
      for (int r = 0; r < 4; ++r) {
        int w  = tid + r * 1024;            // 0..4095
        int pl = w >> 9, q = w & 511;
        int k  = q >> 5, cp = q & 31;
        unsigned v = lds[LOUT_OFF + pl*512 + k*32 + (cp ^ (pl*2))];
        yw[(long)(tile * 16 + h * 8 + pl) * 512 + q] = v;
      }
    }
  }
}

// ---------------- kernel 3: bilinear(l,r) -> equi_linear(Wout) -> out f32 [p][c][k] ----------------
__global__ __launch_bounds__(1024) void bilin_out_mfma(
    const unsigned short* __restrict__ lg, const unsigned short* __restrict__ rgl,
    const float* __restrict__ W, const float* __restrict__ bias, float* __restrict__ out)
{
  extern __shared__ unsigned lds[];
  stage_wA(lds, W);

  const int tid  = threadIdx.x;
  const int wid  = tid >> 6;
  const int lane = tid & 63;
  const int b    = wid;
  const int p16  = lane & 15;
  const int rg4  = lane >> 4;
  const int g    = ga::T.gr[b];
  const bool he  = ga::T.he0[b] != 0;
  const int ew   = he ? ga::T.e0w[b] : 0;
  const int sb   = ga::T.src[b];
  // bilinear thread mapping: wave-uniform gp/join split, coalesced l/r loads
  const int bp = (tid >> 5) & 15;                    // position in tile
  const int bc = (tid & 31) | ((tid >> 9) << 5);     // channel 0..63

  f32x4 bias4[4];
  if (b == 0) {
    #pragma unroll
    for (int mt = 0; mt < 4; ++mt)
      bias4[mt] = *reinterpret_cast<const f32x4*>(&bias[mt*16 + rg4*4]);
  }
  __syncthreads();

  unsigned short* mf = (unsigned short*)&lds[MF_OFF];
  float* lf = (float*)lds;

  for (int it = 0; it < ITERS; ++it) {
    const int tile = it * NBLK + blockIdx.x;

    // ---- bilinear: per-(p,c) thread ----
    const long pb = (long)(tile * 16 + bp) * 1024;
    float lv[16], rv[16];
    #pragma unroll
    for (int k = 0; k < 16; ++k) {
      lv[k] = bf2f(lg[pb + k*64 + bc]);
      rv[k] = bf2f(rgl[pb + k*64 + bc]);
    }
    float m[16];
    #pragma unroll
    for (int k = 0; k < 16; ++k) m[k] = 0.f;
    if (bc < 32) {
      #pragma unroll
      for (int i = 0; i < 16; ++i)
        #pragma unroll
        for (int j = 0; j < 16; ++j) {
          if (ga::T.sg[i*16 + j] > 0)      m[ga::T.kg[i*16 + j]] = fmaf( lv[i], rv[j], m[ga::T.kg[i*16 + j]]);
          else if (ga::T.sg[i*16 + j] < 0) m[ga::T.kg[i*16 + j]] = fmaf(-lv[i], rv[j], m[ga::T.kg[i*16 + j]]);
        }
    } else {
      #pragma unroll
      for (int i = 0; i < 16; ++i)
        #pragma unroll
        for (int j = 0; j < 16; ++j) {
          if (ga::T.sj[i*16 + j] > 0)      m[ga::T.kj[i*16 + j]] = fmaf( lv[i], rv[j], m[ga::T.kj[i*16 + j]]);
          else if (ga::T.sj[i*16 + j] < 0) m[ga::T.kj[i*16 + j]] = fmaf(-lv[i], rv[j], m[ga::T.kj[i*16 + j]]);
        }
    }
    const int ksw = bc >> 5, rgw = (bc >> 3) & 3, jw = bc & 7;
    __syncthreads();   // prev-tile GEMM done with mfrag
    #pragma unroll
    for (int k = 0; k < 16; ++k) {
      unsigned short us = (unsigned short)(cvt_pk_bf16(m[k], m[k]) & 0xffffu);
      mf[((k*2 + ksw)*64 + bp + rgw*16)*8 + jw] = us;
    }
    __syncthreads();

    // ---- out GEMM ----
    f32x4 acc[4];
    #pragma unroll
    for (int mt = 0; mt < 4; ++mt) acc[mt] = (f32x4){0.f, 0.f, 0.f, 0.f};
    #pragma unroll
    for (int ks = 0; ks < 2; ++ks) {
      bf16x8 bm = *reinterpret_cast<const bf16x8*>(&lds[MF_OFF + ((b*2 + ks)*64 + lane)*4]);
      #pragma unroll
      for (int mt = 0; mt < 4; ++mt) {
        bf16x8 a = *reinterpret_cast<const bf16x8*>(&lds[(((g*4 + mt)*2 + ks)*64 + lane)*4]);
        acc[mt] = __builtin_amdgcn_mfma_f32_16x16x32_bf16(a, bm, acc[mt], 0, 0, 0);
      }
    }
    if (he) {
      #pragma unroll
      for (int ks = 0; ks < 2; ++ks) {
        bf16x8 bs = *reinterpret_cast<const bf16x8*>(&lds[MF_OFF + ((sb*2 + ks)*64 + lane)*4]);
        #pragma unroll
        for (int mt = 0; mt < 4; ++mt) {
          bf16x8 a = *reinterpret_cast<const bf16x8*>(&lds[(((ew*4 + mt)*2 + ks)*64 + lane)*4]);
          acc[mt] = __builtin_amdgcn_mfma_f32_16x16x32_bf16(a, bs, acc[mt], 0, 0, 0);
        }
      }
    }
    if (b == 0) {
      #pragma unroll
      for (int mt = 0; mt < 4; ++mt) acc[mt] += bias4[mt];
    }

    // ---- f32 C-write (k-rotated swizzle) + coalesced flush, in p-halves ----
    #pragma unroll
    for (int h = 0; h < 2; ++h) {
      __syncthreads();
      if ((p16 >> 3) == h) {
        int pl = p16 & 7;
        #pragma unroll
        for (int mt = 0; mt < 4; ++mt)
          #pragma unroll
          for (int j = 0; j < 4; ++j) {
            int c = mt*16 + rg4*4 + j;
            lf[LF_OFF + pl*1025 + c*16 + ((b + 4*rg4) & 15)] = acc[mt][j];
          }
      }
      __syncthreads();
      #pragma unroll
      for (int r = 0; r < 8; ++r) {
        int w  = tid + r * 1024;            // 0..8191
        int pl = w >> 10, q = w & 1023;
        int c  = q >> 4, k = q & 15;
        float v = lf[LF_OFF + pl*1025 + c*16 + ((k + 4*((c >> 2) & 3)) & 15)];
        out[(long)(tile * 16 + h * 8 + pl) * 1024 + q] = v;
      }
    }
  }
}

// ---------------- launch ----------------
extern "C" void kernel_launch(void* const* d_in, const int* in_sizes, int n_in,
                              void* d_out, int out_size, void* d_ws, size_t ws_size,
                              hipStream_t stream) {
  (void)in_sizes; (void)n_in; (void)out_size; (void)ws_size;
  const float* mv1 = (const float*)d_in[0];
  const float* mv2 = (const float*)d_in[1];
  const float* Wl  = (const float*)d_in[2];
  const float* bl  = (const float*)d_in[3];
  const float* Wr  = (const float*)d_in[4];
  const float* br  = (const float*)d_in[5];
  const float* Wo  = (const float*)d_in[6];
  const float* bo  = (const float*)d_in[7];
  float* out = (float*)d_out;
  unsigned short* lbuf = (unsigned short*)d_ws;                       // 32 MB
  unsigned short* rbuf = (unsigned short*)((char*)d_ws + 33554432);   // 32 MB

  const size_t smem1 = K1_WORDS * 4;   // 156224 B
  const size_t smem3 = K3_WORDS * 4;   // 139296 B
  eqlin_mfma<<<NBLK, 1024, smem1, stream>>>(mv1, Wl, bl, lbuf);
  eqlin_mfma<<<NBLK, 1024, smem1, stream>>>(mv2, Wr, br, rbuf);
  bilin_out_mfma<<<NBLK, 1024, smem3, stream>>>(lbuf, rbuf, Wo, bo, out);
}